// Round 6
// baseline (200.603 us; speedup 1.0000x reference)
//
#include <hip/hip_runtime.h>
#include <math.h>

#define DMODEL 2048
#define NEXP   8
#define RANK   16
#define NPAIR  28   // unordered expert pairs C(8,2)

// ---------------- K1: router (logits -> top2 -> pair buckets) ----------------
// 16 tokens/block. lane = (d-quad dg, expert-pair ep, token-octet th).
// Wr read straight from L2 (64 KB, hot); x b128 coalesced; tiny LDS.
__global__ __launch_bounds__(256, 2)
void router_kernel(const float* __restrict__ x,
                   const float* __restrict__ Wr,
                   const float* __restrict__ br,
                   float2* __restrict__ wparams,
                   int* __restrict__ cnt,
                   unsigned short* __restrict__ lists,
                   int nTok)
{
    __shared__ float lg_lds[16][8];

    const int tid = threadIdx.x;
    const int dg  = tid & 31;       // d-quad lane
    const int grp = tid >> 5;       // 0..7
    const int ep  = grp & 3;        // experts 2ep, 2ep+1
    const int th  = grp >> 2;       // token octet 0..1
    const int tbase = blockIdx.x*16 + th*8;

    float a0[8], a1[8];
    #pragma unroll
    for (int t = 0; t < 8; ++t) { a0[t] = 0.f; a1[t] = 0.f; }

    for (int it = 0; it < 16; ++it) {
        const int d0 = it*128 + dg*4;
        const float2 w0 = *(const float2*)&Wr[(d0+0)*NEXP + ep*2];
        const float2 w1 = *(const float2*)&Wr[(d0+1)*NEXP + ep*2];
        const float2 w2 = *(const float2*)&Wr[(d0+2)*NEXP + ep*2];
        const float2 w3 = *(const float2*)&Wr[(d0+3)*NEXP + ep*2];
        #pragma unroll
        for (int t = 0; t < 8; ++t) {
            const float4 xv = *(const float4*)&x[(size_t)(tbase+t)*DMODEL + d0];
            a0[t] = fmaf(xv.x, w0.x, a0[t]);
            a0[t] = fmaf(xv.y, w1.x, a0[t]);
            a0[t] = fmaf(xv.z, w2.x, a0[t]);
            a0[t] = fmaf(xv.w, w3.x, a0[t]);
            a1[t] = fmaf(xv.x, w0.y, a1[t]);
            a1[t] = fmaf(xv.y, w1.y, a1[t]);
            a1[t] = fmaf(xv.z, w2.y, a1[t]);
            a1[t] = fmaf(xv.w, w3.y, a1[t]);
        }
    }
    #pragma unroll
    for (int mm = 1; mm <= 16; mm <<= 1) {
        #pragma unroll
        for (int t = 0; t < 8; ++t) {
            a0[t] += __shfl_xor(a0[t], mm);
            a1[t] += __shfl_xor(a1[t], mm);
        }
    }
    if (dg < 8) {
        lg_lds[th*8 + dg][ep*2 + 0] = a0[dg];
        lg_lds[th*8 + dg][ep*2 + 1] = a1[dg];
    }
    __syncthreads();

    if (tid < 16) {
        const int tok = blockIdx.x*16 + tid;
        if (tok < nTok) {
            float lg[NEXP];
            #pragma unroll
            for (int e = 0; e < NEXP; ++e) lg[e] = lg_lds[tid][e] + br[e];
            int b0 = 0; float v0 = lg[0];
            #pragma unroll
            for (int e = 1; e < NEXP; ++e) { if (lg[e] > v0) { v0 = lg[e]; b0 = e; } }
            int b1 = (b0 == 0) ? 1 : 0; float v1 = lg[b1];
            #pragma unroll
            for (int e = 0; e < NEXP; ++e) { if (e != b0 && lg[e] > v1) { v1 = lg[e]; b1 = e; } }
            const float t = expf(v1 - v0);
            const float wtop = 1.f / (1.f + t);
            const float wsec = t / (1.f + t);
            const int lo = (b0 < b1) ? b0 : b1;
            const int hi = (b0 < b1) ? b1 : b0;
            const float wlo = (b0 < b1) ? wtop : wsec;
            const float whi = (b0 < b1) ? wsec : wtop;
            wparams[tok] = make_float2(wlo, whi);
            const int pidx = lo*(NEXP-1) - (lo*(lo-1))/2 + (hi - lo - 1);
            const int pos = atomicAdd(&cnt[pidx], 1);
            lists[(size_t)pidx*nTok + pos] = (unsigned short)tok;
        }
    }
}

// ---------------- K1.5: block->(pair,tile) maps ----------------
__global__ void prefix_kernel(const int* __restrict__ cnt,
                              int* __restrict__ tots,
                              int* __restrict__ map8,
                              int* __restrict__ map32)
{
    if (threadIdx.x == 0) {
        int a8 = 0, a32 = 0;
        for (int p = 0; p < NPAIR; ++p) {
            const int n = cnt[p];
            const int n8 = (n + 7) >> 3;
            for (int t = 0; t < n8; ++t)  map8[a8++]  = (p << 16) | t;
            const int n32 = (n + 31) >> 5;
            for (int t = 0; t < n32; ++t) map32[a32++] = (p << 16) | t;
        }
        tots[0] = a8;
        tots[1] = a32;
    }
}

// ---------------- K2: down projection, coalesced streaming, no LDS ----------------
// Raw partial dots: hw2[t][ch][k][r] = sum_{d in ch half} x[t][d]*Wd[e_k][d][r].
// 8 tokens/block: lane = (dg = d mod 32, k, token-pair tq). acc[2][16] = 32 VGPRs
// (no spill). x: 128B coalesced; Wd: 4x b128, 32 lanes span 2KB contiguous.
__global__ __launch_bounds__(256, 2)
void down_kernel(const float* __restrict__ x,
                 const float* __restrict__ Wd,
                 const int* __restrict__ cnt,
                 const int* __restrict__ tots,
                 const int* __restrict__ map8,
                 const unsigned short* __restrict__ lists,
                 float* __restrict__ hw2,
                 int nTok)
{
    const int bx = blockIdx.x;
    if (bx >= tots[0]) return;
    const int mp = map8[bx];
    const int p = mp >> 16;
    const int tile = mp & 0xffff;
    const int m = min(8, cnt[p] - tile*8);
    int lo = 0, rem = p;
    while (rem >= (NEXP-1-lo)) { rem -= (NEXP-1-lo); ++lo; }
    const int hi = lo + 1 + rem;
    const int ch = blockIdx.y;         // c-half 0/1

    const int tid = threadIdx.x;
    const int dg = tid & 31;
    const int u  = tid >> 5;
    const int k  = u >> 2;             // expert slot
    const int tq = u & 3;              // token pair
    const int e  = k ? hi : lo;

    int toks[2];
    #pragma unroll
    for (int i = 0; i < 2; ++i) {
        const int slot = tq*2 + i;
        toks[i] = lists[(size_t)p*nTok + tile*8 + ((slot < m) ? slot : 0)];
    }

    const float* wdp = Wd + (size_t)e * (DMODEL*RANK);

    float acc[2][16];
    #pragma unroll
    for (int i = 0; i < 2; ++i)
        #pragma unroll
        for (int r = 0; r < 16; ++r) acc[i][r] = 0.f;

    const int dbase = ch*1024 + dg;
    #pragma unroll 2
    for (int jj = 0; jj < 32; ++jj) {
        const int d = dbase + jj*32;
        const float4 w0 = *(const float4*)&wdp[d*RANK + 0];
        const float4 w1 = *(const float4*)&wdp[d*RANK + 4];
        const float4 w2 = *(const float4*)&wdp[d*RANK + 8];
        const float4 w3 = *(const float4*)&wdp[d*RANK + 12];
        float xv[2];
        xv[0] = x[(size_t)toks[0]*DMODEL + d];
        xv[1] = x[(size_t)toks[1]*DMODEL + d];
        #pragma unroll
        for (int i = 0; i < 2; ++i) {
            acc[i][0]  = fmaf(xv[i], w0.x, acc[i][0]);
            acc[i][1]  = fmaf(xv[i], w0.y, acc[i][1]);
            acc[i][2]  = fmaf(xv[i], w0.z, acc[i][2]);
            acc[i][3]  = fmaf(xv[i], w0.w, acc[i][3]);
            acc[i][4]  = fmaf(xv[i], w1.x, acc[i][4]);
            acc[i][5]  = fmaf(xv[i], w1.y, acc[i][5]);
            acc[i][6]  = fmaf(xv[i], w1.z, acc[i][6]);
            acc[i][7]  = fmaf(xv[i], w1.w, acc[i][7]);
            acc[i][8]  = fmaf(xv[i], w2.x, acc[i][8]);
            acc[i][9]  = fmaf(xv[i], w2.y, acc[i][9]);
            acc[i][10] = fmaf(xv[i], w2.z, acc[i][10]);
            acc[i][11] = fmaf(xv[i], w2.w, acc[i][11]);
            acc[i][12] = fmaf(xv[i], w3.x, acc[i][12]);
            acc[i][13] = fmaf(xv[i], w3.y, acc[i][13]);
            acc[i][14] = fmaf(xv[i], w3.z, acc[i][14]);
            acc[i][15] = fmaf(xv[i], w3.w, acc[i][15]);
        }
    }

    // butterfly allreduce over the 32 dg-lanes
    #pragma unroll
    for (int mm = 1; mm <= 16; mm <<= 1)
        #pragma unroll
        for (int i = 0; i < 2; ++i)
            #pragma unroll
            for (int r = 0; r < 16; ++r)
                acc[i][r] += __shfl_xor(acc[i][r], mm);

    // writers: dg<8 -> (i = dg>>2, rq = dg&3)
    if (dg < 8) {
        const int i  = dg >> 2;
        const int rq = dg & 3;
        const int slot = tq*2 + i;
        if (slot < m) {
            float4 v;
            v.x = acc[i][rq*4+0];
            v.y = acc[i][rq*4+1];
            v.z = acc[i][rq*4+2];
            v.w = acc[i][rq*4+3];
            *(float4*)&hw2[(size_t)toks[i]*64 + ch*32 + k*16 + rq*4] = v;
        }
    }
}

// ---------------- K3: up projection (finalizes h inline) ----------------
__global__ __launch_bounds__(256, 2)
void up_kernel(const float* __restrict__ Wu,
               const float* __restrict__ bu,
               const float* __restrict__ bd,
               const float2* __restrict__ wparams,
               const int* __restrict__ cnt,
               const int* __restrict__ tots,
               const int* __restrict__ map32,
               const unsigned short* __restrict__ lists,
               const float* __restrict__ hw2,
               float* __restrict__ out,
               int nTok)
{
    const int bx = blockIdx.x;
    if (bx >= tots[1]) return;
    const int mp = map32[bx];
    const int p = mp >> 16;
    const int tile = mp & 0xffff;
    const int m = min(32, cnt[p] - tile*32);
    int lo = 0, rem = p;
    while (rem >= (NEXP-1-lo)) { rem -= (NEXP-1-lo); ++lo; }
    const int hi = lo + 1 + rem;
    const int cc = blockIdx.y;        // d-chunk of 256

    __shared__ float wu_lds[2][16][256];   // 32 KB
    __shared__ float h_lds[32][36];        // 4.6 KB
    __shared__ float w2_lds[2][32];
    __shared__ int   tok_lds[32];

    const int tid = threadIdx.x;

    if (tid < 32) {
        const int idx = tile*32 + ((tid < m) ? tid : 0);
        const int t = lists[(size_t)p*nTok + idx];
        tok_lds[tid] = t;
        const float2 w = wparams[t];
        w2_lds[0][tid] = (tid < m) ? w.x : 0.f;
        w2_lds[1][tid] = (tid < m) ? w.y : 0.f;
    }

    // stage Wu chunk: direct global->LDS
    #pragma unroll
    for (int i = 0; i < 8; ++i) {
        const int f  = i*1024 + tid*4;   // 0..8191
        const int kk = f >> 12;
        const int rr = (f >> 8) & 15;
        const int dd = f & 255;
        const int es = kk ? hi : lo;
        *(float4*)&wu_lds[kk][rr][dd] =
            *(const float4*)&Wu[(size_t)es*(RANK*DMODEL) + (size_t)rr*DMODEL + cc*256 + dd];
    }
    __syncthreads();

    {   // gather + finalize h' = relu(sum of c-half partials + bd) * w
        const int t8 = tid >> 3;          // token slot 0..31
        const int kk = (tid >> 2) & 1;
        const int rq = tid & 3;
        const int e2 = kk ? hi : lo;
        const float* hp = &hw2[(size_t)tok_lds[t8]*64 + kk*16 + rq*4];
        const float4 s0 = *(const float4*)&hp[0];
        const float4 s1 = *(const float4*)&hp[32];
        const float4 bdv = *(const float4*)&bd[e2*RANK + rq*4];
        const float w = w2_lds[kk][t8];
        float4 h;
        h.x = fmaxf(s0.x + s1.x + bdv.x, 0.f) * w;
        h.y = fmaxf(s0.y + s1.y + bdv.y, 0.f) * w;
        h.z = fmaxf(s0.z + s1.z + bdv.z, 0.f) * w;
        h.w = fmaxf(s0.w + s1.w + bdv.w, 0.f) * w;
        *(float4*)&h_lds[t8][kk*16 + rq*4] = h;
    }
    __syncthreads();

    const int dg = tid & 31;    // 32 d-groups (4 floats each, two halves)
    const int tq = tid >> 5;    // 8 token quads
    float4 a0[4], a1[4];
    #pragma unroll
    for (int i = 0; i < 4; ++i) { a0[i] = make_float4(0,0,0,0); a1[i] = make_float4(0,0,0,0); }

    #pragma unroll 8
    for (int kr = 0; kr < 32; ++kr) {
        const int kk = kr >> 4, rr = kr & 15;
        const float4 u0 = *(const float4*)&wu_lds[kk][rr][dg*4];
        const float4 u1 = *(const float4*)&wu_lds[kk][rr][128 + dg*4];
        #pragma unroll
        for (int i = 0; i < 4; ++i) {
            const float hv = h_lds[tq*4 + i][kr];
            a0[i].x = fmaf(hv, u0.x, a0[i].x);
            a0[i].y = fmaf(hv, u0.y, a0[i].y);
            a0[i].z = fmaf(hv, u0.z, a0[i].z);
            a0[i].w = fmaf(hv, u0.w, a0[i].w);
            a1[i].x = fmaf(hv, u1.x, a1[i].x);
            a1[i].y = fmaf(hv, u1.y, a1[i].y);
            a1[i].z = fmaf(hv, u1.z, a1[i].z);
            a1[i].w = fmaf(hv, u1.w, a1[i].w);
        }
    }

    const float4 bl0 = *(const float4*)&bu[(size_t)lo*DMODEL + cc*256 + dg*4];
    const float4 bl1 = *(const float4*)&bu[(size_t)lo*DMODEL + cc*256 + 128 + dg*4];
    const float4 bh0 = *(const float4*)&bu[(size_t)hi*DMODEL + cc*256 + dg*4];
    const float4 bh1 = *(const float4*)&bu[(size_t)hi*DMODEL + cc*256 + 128 + dg*4];

    #pragma unroll
    for (int i = 0; i < 4; ++i) {
        const int slot = tq*4 + i;
        if (slot < m) {
            const int t = tok_lds[slot];
            const float wl = w2_lds[0][slot];
            const float wh = w2_lds[1][slot];
            float4 o0 = a0[i], o1 = a1[i];
            o0.x += wl*bl0.x + wh*bh0.x;  o0.y += wl*bl0.y + wh*bh0.y;
            o0.z += wl*bl0.z + wh*bh0.z;  o0.w += wl*bl0.w + wh*bh0.w;
            o1.x += wl*bl1.x + wh*bh1.x;  o1.y += wl*bl1.y + wh*bh1.y;
            o1.z += wl*bl1.z + wh*bh1.z;  o1.w += wl*bl1.w + wh*bh1.w;
            float* op = &out[(size_t)t*DMODEL + cc*256];
            *(float4*)&op[dg*4]       = o0;
            *(float4*)&op[128 + dg*4] = o1;
        }
    }
}

extern "C" void kernel_launch(void* const* d_in, const int* in_sizes, int n_in,
                              void* d_out, int out_size, void* d_ws, size_t ws_size,
                              hipStream_t stream)
{
    (void)n_in; (void)out_size; (void)ws_size;
    const float* x  = (const float*)d_in[0];
    const float* Wr = (const float*)d_in[1];
    const float* br = (const float*)d_in[2];
    const float* Wd = (const float*)d_in[3];
    const float* bd = (const float*)d_in[4];
    const float* Wu = (const float*)d_in[5];
    const float* bu = (const float*)d_in[6];
    float* out = (float*)d_out;
    const int nTok = in_sizes[0] / DMODEL;   // 8192

    const int maxb8  = (nTok + 7)/8 + NPAIR;
    const int maxb32 = (nTok + 31)/32 + NPAIR;

    // ws layout: cnt | tots | map8 | map32 | wparams | lists | hw2
    char* base = (char*)d_ws;
    int* cnt  = (int*)(base);                 // 28 ints
    int* tots = (int*)(base + 128);           // 2 ints
    size_t off = 256;
    int* map8 = (int*)(base + off);
    off += (size_t)maxb8*4;  off = (off + 255) & ~(size_t)255;
    int* map32 = (int*)(base + off);
    off += (size_t)maxb32*4; off = (off + 255) & ~(size_t)255;
    float2* wparams = (float2*)(base + off);
    off += (size_t)nTok*sizeof(float2);
    unsigned short* lists = (unsigned short*)(base + off);
    off += (size_t)NPAIR*nTok*sizeof(unsigned short);
    off = (off + 255) & ~(size_t)255;
    float* hw2 = (float*)(base + off);

    hipMemsetAsync(d_ws, 0, 256, stream);
    const int ntiles16 = (nTok + 15)/16;
    router_kernel<<<ntiles16, 256, 0, stream>>>(x, Wr, br, wparams, cnt, lists, nTok);
    prefix_kernel<<<1, 64, 0, stream>>>(cnt, tots, map8, map32);
    dim3 gdown(maxb8, 2);
    down_kernel<<<gdown, 256, 0, stream>>>(x, Wd, cnt, tots, map8, lists, hw2, nTok);
    dim3 gup(maxb32, 8);
    up_kernel<<<gup, 256, 0, stream>>>(Wu, bu, bd, wparams, cnt, tots, map32, lists, hw2, out, nTok);
}

// Round 7
// 165.045 us; speedup vs baseline: 1.2154x; 1.2154x over previous
//
#include <hip/hip_runtime.h>
#include <math.h>

#define DMODEL 2048
#define NEXP   8
#define RANK   16
#define NPAIR  28   // unordered expert pairs C(8,2)

// ---------------- K1: router (logits -> top2 -> pair buckets) ----------------
// 16 tokens/block. lane = (d-quad dg, expert-pair ep, token-octet th).
// Wr read straight from L2 (64 KB, hot); x b128 coalesced; tiny LDS.
__global__ __launch_bounds__(256, 2)
void router_kernel(const float* __restrict__ x,
                   const float* __restrict__ Wr,
                   const float* __restrict__ br,
                   float2* __restrict__ wparams,
                   int* __restrict__ cnt,
                   unsigned short* __restrict__ lists,
                   int nTok)
{
    __shared__ float lg_lds[16][8];

    const int tid = threadIdx.x;
    const int dg  = tid & 31;       // d-quad lane
    const int grp = tid >> 5;       // 0..7
    const int ep  = grp & 3;        // experts 2ep, 2ep+1
    const int th  = grp >> 2;       // token octet 0..1
    const int tbase = blockIdx.x*16 + th*8;

    float a0[8], a1[8];
    #pragma unroll
    for (int t = 0; t < 8; ++t) { a0[t] = 0.f; a1[t] = 0.f; }

    for (int it = 0; it < 16; ++it) {
        const int d0 = it*128 + dg*4;
        const float2 w0 = *(const float2*)&Wr[(d0+0)*NEXP + ep*2];
        const float2 w1 = *(const float2*)&Wr[(d0+1)*NEXP + ep*2];
        const float2 w2 = *(const float2*)&Wr[(d0+2)*NEXP + ep*2];
        const float2 w3 = *(const float2*)&Wr[(d0+3)*NEXP + ep*2];
        #pragma unroll
        for (int t = 0; t < 8; ++t) {
            const float4 xv = *(const float4*)&x[(size_t)(tbase+t)*DMODEL + d0];
            a0[t] = fmaf(xv.x, w0.x, a0[t]);
            a0[t] = fmaf(xv.y, w1.x, a0[t]);
            a0[t] = fmaf(xv.z, w2.x, a0[t]);
            a0[t] = fmaf(xv.w, w3.x, a0[t]);
            a1[t] = fmaf(xv.x, w0.y, a1[t]);
            a1[t] = fmaf(xv.y, w1.y, a1[t]);
            a1[t] = fmaf(xv.z, w2.y, a1[t]);
            a1[t] = fmaf(xv.w, w3.y, a1[t]);
        }
    }
    #pragma unroll
    for (int mm = 1; mm <= 16; mm <<= 1) {
        #pragma unroll
        for (int t = 0; t < 8; ++t) {
            a0[t] += __shfl_xor(a0[t], mm);
            a1[t] += __shfl_xor(a1[t], mm);
        }
    }
    if (dg < 8) {
        lg_lds[th*8 + dg][ep*2 + 0] = a0[dg];
        lg_lds[th*8 + dg][ep*2 + 1] = a1[dg];
    }
    __syncthreads();

    if (tid < 16) {
        const int tok = blockIdx.x*16 + tid;
        if (tok < nTok) {
            float lg[NEXP];
            #pragma unroll
            for (int e = 0; e < NEXP; ++e) lg[e] = lg_lds[tid][e] + br[e];
            int b0 = 0; float v0 = lg[0];
            #pragma unroll
            for (int e = 1; e < NEXP; ++e) { if (lg[e] > v0) { v0 = lg[e]; b0 = e; } }
            int b1 = (b0 == 0) ? 1 : 0; float v1 = lg[b1];
            #pragma unroll
            for (int e = 0; e < NEXP; ++e) { if (e != b0 && lg[e] > v1) { v1 = lg[e]; b1 = e; } }
            const float t = expf(v1 - v0);
            const float wtop = 1.f / (1.f + t);
            const float wsec = t / (1.f + t);
            const int lo = (b0 < b1) ? b0 : b1;
            const int hi = (b0 < b1) ? b1 : b0;
            const float wlo = (b0 < b1) ? wtop : wsec;
            const float whi = (b0 < b1) ? wsec : wtop;
            wparams[tok] = make_float2(wlo, whi);
            const int pidx = lo*(NEXP-1) - (lo*(lo-1))/2 + (hi - lo - 1);
            const int pos = atomicAdd(&cnt[pidx], 1);
            lists[(size_t)pidx*nTok + pos] = (unsigned short)tok;
        }
    }
}

// ---------------- K1.5: block->(pair,tile) maps (wave-scan parallel) ----------------
__global__ void prefix_kernel(const int* __restrict__ cnt,
                              int* __restrict__ tots,
                              int* __restrict__ map8,
                              int* __restrict__ map32)
{
    const int lane = threadIdx.x;   // 64 threads, lanes 0..27 active
    const int n   = (lane < NPAIR) ? cnt[lane] : 0;
    const int n8  = (n + 7) >> 3;
    const int n32 = (n + 31) >> 5;
    int s8 = n8, s32 = n32;
    #pragma unroll
    for (int off = 1; off < 32; off <<= 1) {
        const int u8  = __shfl_up(s8, off);
        const int u32 = __shfl_up(s32, off);
        if (lane >= off) { s8 += u8; s32 += u32; }
    }
    if (lane < NPAIR) {
        const int b8 = s8 - n8;
        for (int t = 0; t < n8; ++t)  map8[b8 + t]  = (lane << 16) | t;
        const int b32 = s32 - n32;
        for (int t = 0; t < n32; ++t) map32[b32 + t] = (lane << 16) | t;
    }
    if (lane == NPAIR - 1) { tots[0] = s8; tots[1] = s32; }
}

// ---------------- K2: down projection, coalesced streaming, no LDS ----------------
// Raw partial dots: hw2[t][ch][k][r] = sum_{d in ch half} x[t][d]*Wd[e_k][d][r].
// 8 tokens/block: lane = (dg = d mod 32, k, token-pair tq). v[32] flat accumulator,
// ALL indices compile-time (rule #20: runtime-indexed reg arrays -> scratch).
// Reduce: split butterfly (keep half / ship half), lane dg ends with value
// idx = bitrev5(dg); single scalar store.
__global__ __launch_bounds__(256, 2)
void down_kernel(const float* __restrict__ x,
                 const float* __restrict__ Wd,
                 const int* __restrict__ cnt,
                 const int* __restrict__ tots,
                 const int* __restrict__ map8,
                 const unsigned short* __restrict__ lists,
                 float* __restrict__ hw2,
                 int nTok)
{
    const int bx = blockIdx.x;
    if (bx >= tots[0]) return;
    const int mp = map8[bx];
    const int p = mp >> 16;
    const int tile = mp & 0xffff;
    const int m = min(8, cnt[p] - tile*8);
    int lo = 0, rem = p;
    while (rem >= (NEXP-1-lo)) { rem -= (NEXP-1-lo); ++lo; }
    const int hi = lo + 1 + rem;
    const int ch = blockIdx.y;         // c-half 0/1

    const int tid = threadIdx.x;
    const int dg = tid & 31;
    const int u  = tid >> 5;
    const int k  = u >> 2;             // expert slot
    const int tq = u & 3;              // token pair
    const int e  = k ? hi : lo;

    int toks[2];
    #pragma unroll
    for (int i = 0; i < 2; ++i) {
        const int slot = tq*2 + i;
        toks[i] = lists[(size_t)p*nTok + tile*8 + ((slot < m) ? slot : 0)];
    }

    const float* wdp = Wd + (size_t)e * (DMODEL*RANK);

    float v[32];                       // v[i*16+r]
    #pragma unroll
    for (int i = 0; i < 32; ++i) v[i] = 0.f;

    const int dbase = ch*1024 + dg;
    #pragma unroll 2
    for (int jj = 0; jj < 32; ++jj) {
        const int d = dbase + jj*32;
        const float4 w0 = *(const float4*)&wdp[d*RANK + 0];
        const float4 w1 = *(const float4*)&wdp[d*RANK + 4];
        const float4 w2 = *(const float4*)&wdp[d*RANK + 8];
        const float4 w3 = *(const float4*)&wdp[d*RANK + 12];
        float xv[2];
        xv[0] = x[(size_t)toks[0]*DMODEL + d];
        xv[1] = x[(size_t)toks[1]*DMODEL + d];
        #pragma unroll
        for (int i = 0; i < 2; ++i) {
            v[i*16+0]  = fmaf(xv[i], w0.x, v[i*16+0]);
            v[i*16+1]  = fmaf(xv[i], w0.y, v[i*16+1]);
            v[i*16+2]  = fmaf(xv[i], w0.z, v[i*16+2]);
            v[i*16+3]  = fmaf(xv[i], w0.w, v[i*16+3]);
            v[i*16+4]  = fmaf(xv[i], w1.x, v[i*16+4]);
            v[i*16+5]  = fmaf(xv[i], w1.y, v[i*16+5]);
            v[i*16+6]  = fmaf(xv[i], w1.z, v[i*16+6]);
            v[i*16+7]  = fmaf(xv[i], w1.w, v[i*16+7]);
            v[i*16+8]  = fmaf(xv[i], w2.x, v[i*16+8]);
            v[i*16+9]  = fmaf(xv[i], w2.y, v[i*16+9]);
            v[i*16+10] = fmaf(xv[i], w2.z, v[i*16+10]);
            v[i*16+11] = fmaf(xv[i], w2.w, v[i*16+11]);
            v[i*16+12] = fmaf(xv[i], w3.x, v[i*16+12]);
            v[i*16+13] = fmaf(xv[i], w3.y, v[i*16+13]);
            v[i*16+14] = fmaf(xv[i], w3.z, v[i*16+14]);
            v[i*16+15] = fmaf(xv[i], w3.w, v[i*16+15]);
        }
    }

    // split butterfly: each stage keep half, ship half. compile-time indices only.
    #define RSTAGE(STAGE, HALF)                                        \
    {                                                                  \
        const bool up_ = (dg & STAGE) != 0;                            \
        _Pragma("unroll")                                              \
        for (int j = 0; j < HALF; ++j) {                               \
            const float give = up_ ? v[j] : v[j + HALF];               \
            const float keep = up_ ? v[j + HALF] : v[j];               \
            v[j] = keep + __shfl_xor(give, STAGE);                     \
        }                                                              \
    }
    RSTAGE(1, 16)
    RSTAGE(2, 8)
    RSTAGE(4, 4)
    RSTAGE(8, 2)
    RSTAGE(16, 1)
    #undef RSTAGE

    // lane dg holds the full sum for idx = bitrev5(dg): i = idx>>4, r = idx&15
    const int idx = ((dg & 1) << 4) | ((dg & 2) << 2) | (dg & 4) |
                    ((dg & 8) >> 2) | ((dg & 16) >> 4);
    const int i_  = idx >> 4;
    const int r_  = idx & 15;
    const int slot = tq*2 + i_;
    if (slot < m) {
        const int tok = i_ ? toks[1] : toks[0];
        hw2[(size_t)tok*64 + ch*32 + k*16 + r_] = v[0];
    }
}

// ---------------- K3: up projection (finalizes h inline) ----------------
__global__ __launch_bounds__(256, 2)
void up_kernel(const float* __restrict__ Wu,
               const float* __restrict__ bu,
               const float* __restrict__ bd,
               const float2* __restrict__ wparams,
               const int* __restrict__ cnt,
               const int* __restrict__ tots,
               const int* __restrict__ map32,
               const unsigned short* __restrict__ lists,
               const float* __restrict__ hw2,
               float* __restrict__ out,
               int nTok)
{
    const int bx = blockIdx.x;
    if (bx >= tots[1]) return;
    const int mp = map32[bx];
    const int p = mp >> 16;
    const int tile = mp & 0xffff;
    const int m = min(32, cnt[p] - tile*32);
    int lo = 0, rem = p;
    while (rem >= (NEXP-1-lo)) { rem -= (NEXP-1-lo); ++lo; }
    const int hi = lo + 1 + rem;
    const int cc = blockIdx.y;        // d-chunk of 256

    __shared__ float wu_lds[2][16][256];   // 32 KB
    __shared__ float h_lds[32][36];        // 4.6 KB
    __shared__ float w2_lds[2][32];
    __shared__ int   tok_lds[32];

    const int tid = threadIdx.x;

    if (tid < 32) {
        const int idx = tile*32 + ((tid < m) ? tid : 0);
        const int t = lists[(size_t)p*nTok + idx];
        tok_lds[tid] = t;
        const float2 w = wparams[t];
        w2_lds[0][tid] = (tid < m) ? w.x : 0.f;
        w2_lds[1][tid] = (tid < m) ? w.y : 0.f;
    }

    // stage Wu chunk: direct global->LDS
    #pragma unroll
    for (int i = 0; i < 8; ++i) {
        const int f  = i*1024 + tid*4;   // 0..8191
        const int kk = f >> 12;
        const int rr = (f >> 8) & 15;
        const int dd = f & 255;
        const int es = kk ? hi : lo;
        *(float4*)&wu_lds[kk][rr][dd] =
            *(const float4*)&Wu[(size_t)es*(RANK*DMODEL) + (size_t)rr*DMODEL + cc*256 + dd];
    }
    __syncthreads();

    {   // gather + finalize h' = relu(sum of c-half partials + bd) * w
        const int t8 = tid >> 3;          // token slot 0..31
        const int kk = (tid >> 2) & 1;
        const int rq = tid & 3;
        const int e2 = kk ? hi : lo;
        const float* hp = &hw2[(size_t)tok_lds[t8]*64 + kk*16 + rq*4];
        const float4 s0 = *(const float4*)&hp[0];
        const float4 s1 = *(const float4*)&hp[32];
        const float4 bdv = *(const float4*)&bd[e2*RANK + rq*4];
        const float w = w2_lds[kk][t8];
        float4 h;
        h.x = fmaxf(s0.x + s1.x + bdv.x, 0.f) * w;
        h.y = fmaxf(s0.y + s1.y + bdv.y, 0.f) * w;
        h.z = fmaxf(s0.z + s1.z + bdv.z, 0.f) * w;
        h.w = fmaxf(s0.w + s1.w + bdv.w, 0.f) * w;
        *(float4*)&h_lds[t8][kk*16 + rq*4] = h;
    }
    __syncthreads();

    const int dg = tid & 31;    // 32 d-groups (4 floats each, two halves)
    const int tq = tid >> 5;    // 8 token quads
    float4 a0[4], a1[4];
    #pragma unroll
    for (int i = 0; i < 4; ++i) { a0[i] = make_float4(0,0,0,0); a1[i] = make_float4(0,0,0,0); }

    #pragma unroll 8
    for (int kr = 0; kr < 32; ++kr) {
        const int kk = kr >> 4, rr = kr & 15;
        const float4 u0 = *(const float4*)&wu_lds[kk][rr][dg*4];
        const float4 u1 = *(const float4*)&wu_lds[kk][rr][128 + dg*4];
        #pragma unroll
        for (int i = 0; i < 4; ++i) {
            const float hv = h_lds[tq*4 + i][kr];
            a0[i].x = fmaf(hv, u0.x, a0[i].x);
            a0[i].y = fmaf(hv, u0.y, a0[i].y);
            a0[i].z = fmaf(hv, u0.z, a0[i].z);
            a0[i].w = fmaf(hv, u0.w, a0[i].w);
            a1[i].x = fmaf(hv, u1.x, a1[i].x);
            a1[i].y = fmaf(hv, u1.y, a1[i].y);
            a1[i].z = fmaf(hv, u1.z, a1[i].z);
            a1[i].w = fmaf(hv, u1.w, a1[i].w);
        }
    }

    const float4 bl0 = *(const float4*)&bu[(size_t)lo*DMODEL + cc*256 + dg*4];
    const float4 bl1 = *(const float4*)&bu[(size_t)lo*DMODEL + cc*256 + 128 + dg*4];
    const float4 bh0 = *(const float4*)&bu[(size_t)hi*DMODEL + cc*256 + dg*4];
    const float4 bh1 = *(const float4*)&bu[(size_t)hi*DMODEL + cc*256 + 128 + dg*4];

    #pragma unroll
    for (int i = 0; i < 4; ++i) {
        const int slot = tq*4 + i;
        if (slot < m) {
            const int t = tok_lds[slot];
            const float wl = w2_lds[0][slot];
            const float wh = w2_lds[1][slot];
            float4 o0 = a0[i], o1 = a1[i];
            o0.x += wl*bl0.x + wh*bh0.x;  o0.y += wl*bl0.y + wh*bh0.y;
            o0.z += wl*bl0.z + wh*bh0.z;  o0.w += wl*bl0.w + wh*bh0.w;
            o1.x += wl*bl1.x + wh*bh1.x;  o1.y += wl*bl1.y + wh*bh1.y;
            o1.z += wl*bl1.z + wh*bh1.z;  o1.w += wl*bl1.w + wh*bh1.w;
            float* op = &out[(size_t)t*DMODEL + cc*256];
            *(float4*)&op[dg*4]       = o0;
            *(float4*)&op[128 + dg*4] = o1;
        }
    }
}

extern "C" void kernel_launch(void* const* d_in, const int* in_sizes, int n_in,
                              void* d_out, int out_size, void* d_ws, size_t ws_size,
                              hipStream_t stream)
{
    (void)n_in; (void)out_size; (void)ws_size;
    const float* x  = (const float*)d_in[0];
    const float* Wr = (const float*)d_in[1];
    const float* br = (const float*)d_in[2];
    const float* Wd = (const float*)d_in[3];
    const float* bd = (const float*)d_in[4];
    const float* Wu = (const float*)d_in[5];
    const float* bu = (const float*)d_in[6];
    float* out = (float*)d_out;
    const int nTok = in_sizes[0] / DMODEL;   // 8192

    const int maxb8  = (nTok + 7)/8 + NPAIR;
    const int maxb32 = (nTok + 31)/32 + NPAIR;

    // ws layout: cnt | tots | map8 | map32 | wparams | lists | hw2
    char* base = (char*)d_ws;
    int* cnt  = (int*)(base);                 // 28 ints
    int* tots = (int*)(base + 128);           // 2 ints
    size_t off = 256;
    int* map8 = (int*)(base + off);
    off += (size_t)maxb8*4;  off = (off + 255) & ~(size_t)255;
    int* map32 = (int*)(base + off);
    off += (size_t)maxb32*4; off = (off + 255) & ~(size_t)255;
    float2* wparams = (float2*)(base + off);
    off += (size_t)nTok*sizeof(float2);
    unsigned short* lists = (unsigned short*)(base + off);
    off += (size_t)NPAIR*nTok*sizeof(unsigned short);
    off = (off + 255) & ~(size_t)255;
    float* hw2 = (float*)(base + off);

    hipMemsetAsync(d_ws, 0, 256, stream);
    const int ntiles16 = (nTok + 15)/16;
    router_kernel<<<ntiles16, 256, 0, stream>>>(x, Wr, br, wparams, cnt, lists, nTok);
    prefix_kernel<<<1, 64, 0, stream>>>(cnt, tots, map8, map32);
    dim3 gdown(maxb8, 2);
    down_kernel<<<gdown, 256, 0, stream>>>(x, Wd, cnt, tots, map8, lists, hw2, nTok);
    dim3 gup(maxb32, 8);
    up_kernel<<<gup, 256, 0, stream>>>(Wu, bu, bd, wparams, cnt, tots, map32, lists, hw2, out, nTok);
}

// Round 8
// 128.453 us; speedup vs baseline: 1.5617x; 1.2849x over previous
//
#include <hip/hip_runtime.h>
#include <math.h>

#define DMODEL 2048
#define NEXP   8
#define RANK   16
#define NPAIR  28   // unordered expert pairs C(8,2)

// ---------------- K1: router (logits -> top2 -> pair buckets) ----------------
// 16 tokens/block. lane = (d-quad dg, expert-pair ep, token-octet th).
// Wr read straight from L2 (64 KB, hot); x b128 coalesced; tiny LDS.
__global__ __launch_bounds__(256, 2)
void router_kernel(const float* __restrict__ x,
                   const float* __restrict__ Wr,
                   const float* __restrict__ br,
                   float2* __restrict__ wparams,
                   int* __restrict__ cnt,
                   unsigned short* __restrict__ lists,
                   int nTok)
{
    __shared__ float lg_lds[16][8];

    const int tid = threadIdx.x;
    const int dg  = tid & 31;       // d-quad lane
    const int grp = tid >> 5;       // 0..7
    const int ep  = grp & 3;        // experts 2ep, 2ep+1
    const int th  = grp >> 2;       // token octet 0..1
    const int tbase = blockIdx.x*16 + th*8;

    float a0[8], a1[8];
    #pragma unroll
    for (int t = 0; t < 8; ++t) { a0[t] = 0.f; a1[t] = 0.f; }

    for (int it = 0; it < 16; ++it) {
        const int d0 = it*128 + dg*4;
        const float2 w0 = *(const float2*)&Wr[(d0+0)*NEXP + ep*2];
        const float2 w1 = *(const float2*)&Wr[(d0+1)*NEXP + ep*2];
        const float2 w2 = *(const float2*)&Wr[(d0+2)*NEXP + ep*2];
        const float2 w3 = *(const float2*)&Wr[(d0+3)*NEXP + ep*2];
        #pragma unroll
        for (int t = 0; t < 8; ++t) {
            const float4 xv = *(const float4*)&x[(size_t)(tbase+t)*DMODEL + d0];
            a0[t] = fmaf(xv.x, w0.x, a0[t]);
            a0[t] = fmaf(xv.y, w1.x, a0[t]);
            a0[t] = fmaf(xv.z, w2.x, a0[t]);
            a0[t] = fmaf(xv.w, w3.x, a0[t]);
            a1[t] = fmaf(xv.x, w0.y, a1[t]);
            a1[t] = fmaf(xv.y, w1.y, a1[t]);
            a1[t] = fmaf(xv.z, w2.y, a1[t]);
            a1[t] = fmaf(xv.w, w3.y, a1[t]);
        }
    }
    #pragma unroll
    for (int mm = 1; mm <= 16; mm <<= 1) {
        #pragma unroll
        for (int t = 0; t < 8; ++t) {
            a0[t] += __shfl_xor(a0[t], mm);
            a1[t] += __shfl_xor(a1[t], mm);
        }
    }
    if (dg < 8) {
        lg_lds[th*8 + dg][ep*2 + 0] = a0[dg];
        lg_lds[th*8 + dg][ep*2 + 1] = a1[dg];
    }
    __syncthreads();

    if (tid < 16) {
        const int tok = blockIdx.x*16 + tid;
        if (tok < nTok) {
            float lg[NEXP];
            #pragma unroll
            for (int e = 0; e < NEXP; ++e) lg[e] = lg_lds[tid][e] + br[e];
            int b0 = 0; float v0 = lg[0];
            #pragma unroll
            for (int e = 1; e < NEXP; ++e) { if (lg[e] > v0) { v0 = lg[e]; b0 = e; } }
            int b1 = (b0 == 0) ? 1 : 0; float v1 = lg[b1];
            #pragma unroll
            for (int e = 0; e < NEXP; ++e) { if (e != b0 && lg[e] > v1) { v1 = lg[e]; b1 = e; } }
            const float t = expf(v1 - v0);
            const float wtop = 1.f / (1.f + t);
            const float wsec = t / (1.f + t);
            const int lo = (b0 < b1) ? b0 : b1;
            const int hi = (b0 < b1) ? b1 : b0;
            const float wlo = (b0 < b1) ? wtop : wsec;
            const float whi = (b0 < b1) ? wsec : wtop;
            wparams[tok] = make_float2(wlo, whi);
            const int pidx = lo*(NEXP-1) - (lo*(lo-1))/2 + (hi - lo - 1);
            const int pos = atomicAdd(&cnt[pidx], 1);
            lists[(size_t)pidx*nTok + pos] = (unsigned short)tok;
        }
    }
}

// ---------------- K1.5: block->(pair,tile) maps (wave-scan parallel) ----------------
__global__ void prefix_kernel(const int* __restrict__ cnt,
                              int* __restrict__ tots,
                              int* __restrict__ map16,
                              int* __restrict__ map32)
{
    const int lane = threadIdx.x;   // 64 threads, lanes 0..27 active
    const int n    = (lane < NPAIR) ? cnt[lane] : 0;
    const int n16  = (n + 15) >> 4;
    const int n32  = (n + 31) >> 5;
    int s16 = n16, s32 = n32;
    #pragma unroll
    for (int off = 1; off < 32; off <<= 1) {
        const int u16 = __shfl_up(s16, off);
        const int u32 = __shfl_up(s32, off);
        if (lane >= off) { s16 += u16; s32 += u32; }
    }
    if (lane < NPAIR) {
        const int b16 = s16 - n16;
        for (int t = 0; t < n16; ++t) map16[b16 + t] = (lane << 16) | t;
        const int b32 = s32 - n32;
        for (int t = 0; t < n32; ++t) map32[b32 + t] = (lane << 16) | t;
    }
    if (lane == NPAIR - 1) { tots[0] = s16; tots[1] = s32; }
}

// ---------------- K2: down projection, streaming + manual even/odd pipeline ----------------
// Raw partial dots: hw2[t][ch][k][r] = sum_{d in ch half} x[t][d]*Wd[e_k][d][r].
// 16 tokens/block: lane = (dg = d mod 32, k, token-quad tq). v[64] flat accumulator,
// ALL indices compile-time (rule #20). Named-register A/B prefetch breaks the
// load->waitcnt->FMA serial chain (round-7 lesson: compiler won't pipeline on its own).
// Reduce: split butterfly (5 stages), lane ends with a float2 of consecutive ranks.
__global__ __launch_bounds__(256, 2)
void down_kernel(const float* __restrict__ x,
                 const float* __restrict__ Wd,
                 const int* __restrict__ cnt,
                 const int* __restrict__ tots,
                 const int* __restrict__ map16,
                 const unsigned short* __restrict__ lists,
                 float* __restrict__ hw2,
                 int nTok)
{
    const int bx = blockIdx.x;
    if (bx >= tots[0]) return;
    const int mp = map16[bx];
    const int p = mp >> 16;
    const int tile = mp & 0xffff;
    const int m = min(16, cnt[p] - tile*16);
    int lo = 0, rem = p;
    while (rem >= (NEXP-1-lo)) { rem -= (NEXP-1-lo); ++lo; }
    const int hi = lo + 1 + rem;
    const int ch = blockIdx.y;         // c-half 0/1

    const int tid = threadIdx.x;
    const int dg = tid & 31;
    const int u  = tid >> 5;
    const int k  = u >> 2;             // expert slot
    const int tq = u & 3;              // token quad
    const int e  = k ? hi : lo;

    int tks[4];
    #pragma unroll
    for (int i = 0; i < 4; ++i) {
        const int slot = tq*4 + i;
        tks[i] = lists[(size_t)p*nTok + tile*16 + ((slot < m) ? slot : 0)];
    }
    const int dbase = ch*1024 + dg;
    const float* x0 = x + (size_t)tks[0]*DMODEL + dbase;
    const float* x1 = x + (size_t)tks[1]*DMODEL + dbase;
    const float* x2 = x + (size_t)tks[2]*DMODEL + dbase;
    const float* x3 = x + (size_t)tks[3]*DMODEL + dbase;
    const float* wp = Wd + (size_t)e*(DMODEL*RANK) + (size_t)dbase*RANK;

    float v[64];                       // v[i*16 + r]
    #pragma unroll
    for (int i = 0; i < 64; ++i) v[i] = 0.f;

    // prefetch iteration 0 into the A set
    float4 wA0 = *(const float4*)(wp + 0);
    float4 wA1 = *(const float4*)(wp + 4);
    float4 wA2 = *(const float4*)(wp + 8);
    float4 wA3 = *(const float4*)(wp + 12);
    float xA0 = x0[0], xA1 = x1[0], xA2 = x2[0], xA3 = x3[0];

    #define FMA16(XV, W0, W1, W2, W3, B)                                \
        v[B+0]  = fmaf(XV, W0.x, v[B+0]);                               \
        v[B+1]  = fmaf(XV, W0.y, v[B+1]);                               \
        v[B+2]  = fmaf(XV, W0.z, v[B+2]);                               \
        v[B+3]  = fmaf(XV, W0.w, v[B+3]);                               \
        v[B+4]  = fmaf(XV, W1.x, v[B+4]);                               \
        v[B+5]  = fmaf(XV, W1.y, v[B+5]);                               \
        v[B+6]  = fmaf(XV, W1.z, v[B+6]);                               \
        v[B+7]  = fmaf(XV, W1.w, v[B+7]);                               \
        v[B+8]  = fmaf(XV, W2.x, v[B+8]);                               \
        v[B+9]  = fmaf(XV, W2.y, v[B+9]);                               \
        v[B+10] = fmaf(XV, W2.z, v[B+10]);                              \
        v[B+11] = fmaf(XV, W2.w, v[B+11]);                              \
        v[B+12] = fmaf(XV, W3.x, v[B+12]);                              \
        v[B+13] = fmaf(XV, W3.y, v[B+13]);                              \
        v[B+14] = fmaf(XV, W3.z, v[B+14]);                              \
        v[B+15] = fmaf(XV, W3.w, v[B+15]);

    for (int jj = 0; jj < 32; jj += 2) {
        // issue iteration jj+1 loads into B, then compute jj from A
        const int dB = (jj + 1) * 32;
        const float* wpb = wp + (size_t)dB * RANK;
        float4 wB0 = *(const float4*)(wpb + 0);
        float4 wB1 = *(const float4*)(wpb + 4);
        float4 wB2 = *(const float4*)(wpb + 8);
        float4 wB3 = *(const float4*)(wpb + 12);
        float xB0 = x0[dB], xB1 = x1[dB], xB2 = x2[dB], xB3 = x3[dB];

        FMA16(xA0, wA0, wA1, wA2, wA3, 0)
        FMA16(xA1, wA0, wA1, wA2, wA3, 16)
        FMA16(xA2, wA0, wA1, wA2, wA3, 32)
        FMA16(xA3, wA0, wA1, wA2, wA3, 48)

        // issue iteration jj+2 loads into A (wraps to 0 at the end: harmless reload)
        const int dA = ((jj + 2) & 31) * 32;
        const float* wpa = wp + (size_t)dA * RANK;
        wA0 = *(const float4*)(wpa + 0);
        wA1 = *(const float4*)(wpa + 4);
        wA2 = *(const float4*)(wpa + 8);
        wA3 = *(const float4*)(wpa + 12);
        xA0 = x0[dA]; xA1 = x1[dA]; xA2 = x2[dA]; xA3 = x3[dA];

        FMA16(xB0, wB0, wB1, wB2, wB3, 0)
        FMA16(xB1, wB0, wB1, wB2, wB3, 16)
        FMA16(xB2, wB0, wB1, wB2, wB3, 32)
        FMA16(xB3, wB0, wB1, wB2, wB3, 48)
    }
    #undef FMA16

    // split butterfly: each stage keep half, ship half. compile-time indices only.
    #define RSTAGE(STAGE, HALF)                                        \
    {                                                                  \
        const bool up_ = (dg & STAGE) != 0;                            \
        _Pragma("unroll")                                              \
        for (int j = 0; j < HALF; ++j) {                               \
            const float give = up_ ? v[j] : v[j + HALF];               \
            const float keep = up_ ? v[j + HALF] : v[j];               \
            v[j] = keep + __shfl_xor(give, STAGE);                     \
        }                                                              \
    }
    RSTAGE(1, 32)
    RSTAGE(2, 16)
    RSTAGE(4, 8)
    RSTAGE(8, 4)
    RSTAGE(16, 2)
    #undef RSTAGE

    // lane dg holds sums for idx0 and idx0+1 where
    // idx0 = lanebit0<<5 | lanebit1<<4 | lanebit2<<3 | lanebit3<<2 | lanebit4<<1
    const int idx0 = ((dg & 1) << 5) | ((dg & 2) << 3) | ((dg & 4) << 1) |
                     ((dg & 8) >> 1) | ((dg & 16) >> 3);
    const int i_ = idx0 >> 4;          // token within quad
    const int r_ = idx0 & 15;          // even rank
    const int slot = tq*4 + i_;
    if (slot < m) {
        const int tok = (i_ & 2) ? ((i_ & 1) ? tks[3] : tks[2])
                                 : ((i_ & 1) ? tks[1] : tks[0]);
        float2 st; st.x = v[0]; st.y = v[1];
        *(float2*)&hw2[(size_t)tok*64 + ch*32 + k*16 + r_] = st;
    }
}

// ---------------- K3: up projection (finalizes h inline) ----------------
__global__ __launch_bounds__(256, 2)
void up_kernel(const float* __restrict__ Wu,
               const float* __restrict__ bu,
               const float* __restrict__ bd,
               const float2* __restrict__ wparams,
               const int* __restrict__ cnt,
               const int* __restrict__ tots,
               const int* __restrict__ map32,
               const unsigned short* __restrict__ lists,
               const float* __restrict__ hw2,
               float* __restrict__ out,
               int nTok)
{
    const int bx = blockIdx.x;
    if (bx >= tots[1]) return;
    const int mp = map32[bx];
    const int p = mp >> 16;
    const int tile = mp & 0xffff;
    const int m = min(32, cnt[p] - tile*32);
    int lo = 0, rem = p;
    while (rem >= (NEXP-1-lo)) { rem -= (NEXP-1-lo); ++lo; }
    const int hi = lo + 1 + rem;
    const int cc = blockIdx.y;        // d-chunk of 256

    __shared__ float wu_lds[2][16][256];   // 32 KB
    __shared__ float h_lds[32][36];        // 4.6 KB
    __shared__ float w2_lds[2][32];
    __shared__ int   tok_lds[32];

    const int tid = threadIdx.x;

    if (tid < 32) {
        const int idx = tile*32 + ((tid < m) ? tid : 0);
        const int t = lists[(size_t)p*nTok + idx];
        tok_lds[tid] = t;
        const float2 w = wparams[t];
        w2_lds[0][tid] = (tid < m) ? w.x : 0.f;
        w2_lds[1][tid] = (tid < m) ? w.y : 0.f;
    }

    // stage Wu chunk: direct global->LDS
    #pragma unroll
    for (int i = 0; i < 8; ++i) {
        const int f  = i*1024 + tid*4;   // 0..8191
        const int kk = f >> 12;
        const int rr = (f >> 8) & 15;
        const int dd = f & 255;
        const int es = kk ? hi : lo;
        *(float4*)&wu_lds[kk][rr][dd] =
            *(const float4*)&Wu[(size_t)es*(RANK*DMODEL) + (size_t)rr*DMODEL + cc*256 + dd];
    }
    __syncthreads();

    {   // gather + finalize h' = relu(sum of c-half partials + bd) * w
        const int t8 = tid >> 3;          // token slot 0..31
        const int kk = (tid >> 2) & 1;
        const int rq = tid & 3;
        const int e2 = kk ? hi : lo;
        const float* hp = &hw2[(size_t)tok_lds[t8]*64 + kk*16 + rq*4];
        const float4 s0 = *(const float4*)&hp[0];
        const float4 s1 = *(const float4*)&hp[32];
        const float4 bdv = *(const float4*)&bd[e2*RANK + rq*4];
        const float w = w2_lds[kk][t8];
        float4 h;
        h.x = fmaxf(s0.x + s1.x + bdv.x, 0.f) * w;
        h.y = fmaxf(s0.y + s1.y + bdv.y, 0.f) * w;
        h.z = fmaxf(s0.z + s1.z + bdv.z, 0.f) * w;
        h.w = fmaxf(s0.w + s1.w + bdv.w, 0.f) * w;
        *(float4*)&h_lds[t8][kk*16 + rq*4] = h;
    }
    __syncthreads();

    const int dg = tid & 31;    // 32 d-groups (4 floats each, two halves)
    const int tq = tid >> 5;    // 8 token quads
    float4 a0[4], a1[4];
    #pragma unroll
    for (int i = 0; i < 4; ++i) { a0[i] = make_float4(0,0,0,0); a1[i] = make_float4(0,0,0,0); }

    #pragma unroll 8
    for (int kr = 0; kr < 32; ++kr) {
        const int kk = kr >> 4, rr = kr & 15;
        const float4 u0 = *(const float4*)&wu_lds[kk][rr][dg*4];
        const float4 u1 = *(const float4*)&wu_lds[kk][rr][128 + dg*4];
        #pragma unroll
        for (int i = 0; i < 4; ++i) {
            const float hv = h_lds[tq*4 + i][kr];
            a0[i].x = fmaf(hv, u0.x, a0[i].x);
            a0[i].y = fmaf(hv, u0.y, a0[i].y);
            a0[i].z = fmaf(hv, u0.z, a0[i].z);
            a0[i].w = fmaf(hv, u0.w, a0[i].w);
            a1[i].x = fmaf(hv, u1.x, a1[i].x);
            a1[i].y = fmaf(hv, u1.y, a1[i].y);
            a1[i].z = fmaf(hv, u1.z, a1[i].z);
            a1[i].w = fmaf(hv, u1.w, a1[i].w);
        }
    }

    const float4 bl0 = *(const float4*)&bu[(size_t)lo*DMODEL + cc*256 + dg*4];
    const float4 bl1 = *(const float4*)&bu[(size_t)lo*DMODEL + cc*256 + 128 + dg*4];
    const float4 bh0 = *(const float4*)&bu[(size_t)hi*DMODEL + cc*256 + dg*4];
    const float4 bh1 = *(const float4*)&bu[(size_t)hi*DMODEL + cc*256 + 128 + dg*4];

    #pragma unroll
    for (int i = 0; i < 4; ++i) {
        const int slot = tq*4 + i;
        if (slot < m) {
            const int t = tok_lds[slot];
            const float wl = w2_lds[0][slot];
            const float wh = w2_lds[1][slot];
            float4 o0 = a0[i], o1 = a1[i];
            o0.x += wl*bl0.x + wh*bh0.x;  o0.y += wl*bl0.y + wh*bh0.y;
            o0.z += wl*bl0.z + wh*bh0.z;  o0.w += wl*bl0.w + wh*bh0.w;
            o1.x += wl*bl1.x + wh*bh1.x;  o1.y += wl*bl1.y + wh*bh1.y;
            o1.z += wl*bl1.z + wh*bh1.z;  o1.w += wl*bl1.w + wh*bh1.w;
            float* op = &out[(size_t)t*DMODEL + cc*256];
            *(float4*)&op[dg*4]       = o0;
            *(float4*)&op[128 + dg*4] = o1;
        }
    }
}

extern "C" void kernel_launch(void* const* d_in, const int* in_sizes, int n_in,
                              void* d_out, int out_size, void* d_ws, size_t ws_size,
                              hipStream_t stream)
{
    (void)n_in; (void)out_size; (void)ws_size;
    const float* x  = (const float*)d_in[0];
    const float* Wr = (const float*)d_in[1];
    const float* br = (const float*)d_in[2];
    const float* Wd = (const float*)d_in[3];
    const float* bd = (const float*)d_in[4];
    const float* Wu = (const float*)d_in[5];
    const float* bu = (const float*)d_in[6];
    float* out = (float*)d_out;
    const int nTok = in_sizes[0] / DMODEL;   // 8192

    const int maxb16 = (nTok + 15)/16 + NPAIR;
    const int maxb32 = (nTok + 31)/32 + NPAIR;

    // ws layout: cnt | tots | map16 | map32 | wparams | lists | hw2
    char* base = (char*)d_ws;
    int* cnt  = (int*)(base);                 // 28 ints
    int* tots = (int*)(base + 128);           // 2 ints
    size_t off = 256;
    int* map16 = (int*)(base + off);
    off += (size_t)maxb16*4; off = (off + 255) & ~(size_t)255;
    int* map32 = (int*)(base + off);
    off += (size_t)maxb32*4; off = (off + 255) & ~(size_t)255;
    float2* wparams = (float2*)(base + off);
    off += (size_t)nTok*sizeof(float2);
    unsigned short* lists = (unsigned short*)(base + off);
    off += (size_t)NPAIR*nTok*sizeof(unsigned short);
    off = (off + 255) & ~(size_t)255;
    float* hw2 = (float*)(base + off);

    hipMemsetAsync(d_ws, 0, 256, stream);
    const int ntiles16 = (nTok + 15)/16;
    router_kernel<<<ntiles16, 256, 0, stream>>>(x, Wr, br, wparams, cnt, lists, nTok);
    prefix_kernel<<<1, 64, 0, stream>>>(cnt, tots, map16, map32);
    dim3 gdown(maxb16, 2);
    down_kernel<<<gdown, 256, 0, stream>>>(x, Wd, cnt, tots, map16, lists, hw2, nTok);
    dim3 gup(maxb32, 8);
    up_kernel<<<gup, 256, 0, stream>>>(Wu, bu, bd, wparams, cnt, tots, map32, lists, hw2, out, nTok);
}

// Round 9
// 118.193 us; speedup vs baseline: 1.6973x; 1.0868x over previous
//
#include <hip/hip_runtime.h>
#include <math.h>

#define DMODEL 2048
#define NEXP   8
#define RANK   16
#define NPAIR  28   // unordered expert pairs C(8,2)
#define NCH    4    // d-chunks in down kernel (512 each)

// ---------------- K1: router (logits -> top2 -> pair buckets) ----------------
// 8 tokens/block (grid 1024 ~ 4 blocks/CU). The two wave-pairs (th) split the
// d-range; logits combined through a tiny LDS. Wr streamed from L2; x b128
// coalesced, each row read once per block.
__global__ __launch_bounds__(256, 2)
void router_kernel(const float* __restrict__ x,
                   const float* __restrict__ Wr,
                   const float* __restrict__ br,
                   float2* __restrict__ wparams,
                   int* __restrict__ cnt,
                   unsigned short* __restrict__ lists,
                   int nTok)
{
    __shared__ float lg_lds[2][8][8];   // [th][token][expert]

    const int tid = threadIdx.x;
    const int dg  = tid & 31;       // d-quad lane
    const int grp = tid >> 5;       // 0..7
    const int ep  = grp & 3;        // experts 2ep, 2ep+1
    const int th  = grp >> 2;       // d-half 0..1
    const int tbase = blockIdx.x*8;

    float a0[8], a1[8];
    #pragma unroll
    for (int t = 0; t < 8; ++t) { a0[t] = 0.f; a1[t] = 0.f; }

    const int dhb = th*1024;
    for (int it = 0; it < 8; ++it) {
        const int d0 = dhb + it*128 + dg*4;
        const float2 w0 = *(const float2*)&Wr[(d0+0)*NEXP + ep*2];
        const float2 w1 = *(const float2*)&Wr[(d0+1)*NEXP + ep*2];
        const float2 w2 = *(const float2*)&Wr[(d0+2)*NEXP + ep*2];
        const float2 w3 = *(const float2*)&Wr[(d0+3)*NEXP + ep*2];
        #pragma unroll
        for (int t = 0; t < 8; ++t) {
            const float4 xv = *(const float4*)&x[(size_t)(tbase+t)*DMODEL + d0];
            a0[t] = fmaf(xv.x, w0.x, a0[t]);
            a0[t] = fmaf(xv.y, w1.x, a0[t]);
            a0[t] = fmaf(xv.z, w2.x, a0[t]);
            a0[t] = fmaf(xv.w, w3.x, a0[t]);
            a1[t] = fmaf(xv.x, w0.y, a1[t]);
            a1[t] = fmaf(xv.y, w1.y, a1[t]);
            a1[t] = fmaf(xv.z, w2.y, a1[t]);
            a1[t] = fmaf(xv.w, w3.y, a1[t]);
        }
    }
    #pragma unroll
    for (int mm = 1; mm <= 16; mm <<= 1) {
        #pragma unroll
        for (int t = 0; t < 8; ++t) {
            a0[t] += __shfl_xor(a0[t], mm);
            a1[t] += __shfl_xor(a1[t], mm);
        }
    }
    if (dg < 8) {
        lg_lds[th][dg][ep*2 + 0] = a0[dg];
        lg_lds[th][dg][ep*2 + 1] = a1[dg];
    }
    __syncthreads();

    if (tid < 8) {
        const int tok = tbase + tid;
        if (tok < nTok) {
            float lg[NEXP];
            #pragma unroll
            for (int e = 0; e < NEXP; ++e)
                lg[e] = lg_lds[0][tid][e] + lg_lds[1][tid][e] + br[e];
            int b0 = 0; float v0 = lg[0];
            #pragma unroll
            for (int e = 1; e < NEXP; ++e) { if (lg[e] > v0) { v0 = lg[e]; b0 = e; } }
            int b1 = (b0 == 0) ? 1 : 0; float v1 = lg[b1];
            #pragma unroll
            for (int e = 0; e < NEXP; ++e) { if (e != b0 && lg[e] > v1) { v1 = lg[e]; b1 = e; } }
            const float t = expf(v1 - v0);
            const float wtop = 1.f / (1.f + t);
            const float wsec = t / (1.f + t);
            const int lo = (b0 < b1) ? b0 : b1;
            const int hi = (b0 < b1) ? b1 : b0;
            const float wlo = (b0 < b1) ? wtop : wsec;
            const float whi = (b0 < b1) ? wsec : wtop;
            wparams[tok] = make_float2(wlo, whi);
            const int pidx = lo*(NEXP-1) - (lo*(lo-1))/2 + (hi - lo - 1);
            const int pos = atomicAdd(&cnt[pidx], 1);
            lists[(size_t)pidx*nTok + pos] = (unsigned short)tok;
        }
    }
}

// ---------------- K1.5: block->(pair,tile) maps (wave-scan parallel) ----------------
__global__ void prefix_kernel(const int* __restrict__ cnt,
                              int* __restrict__ tots,
                              int* __restrict__ map16,
                              int* __restrict__ map32)
{
    const int lane = threadIdx.x;   // 64 threads, lanes 0..27 active
    const int n    = (lane < NPAIR) ? cnt[lane] : 0;
    const int n16  = (n + 15) >> 4;
    const int n32  = (n + 31) >> 5;
    int s16 = n16, s32 = n32;
    #pragma unroll
    for (int off = 1; off < 32; off <<= 1) {
        const int u16 = __shfl_up(s16, off);
        const int u32 = __shfl_up(s32, off);
        if (lane >= off) { s16 += u16; s32 += u32; }
    }
    if (lane < NPAIR) {
        const int b16 = s16 - n16;
        for (int t = 0; t < n16; ++t) map16[b16 + t] = (lane << 16) | t;
        const int b32 = s32 - n32;
        for (int t = 0; t < n32; ++t) map32[b32 + t] = (lane << 16) | t;
    }
    if (lane == NPAIR - 1) { tots[0] = s16; tots[1] = s32; }
}

// ---------------- K2: down projection, streaming + even/odd pipeline, 4 d-chunks ----
// Raw partial dots: hw2[t][ch][k][r] = sum_{d in chunk ch} x[t][d]*Wd[e_k][d][r].
// 16 tokens/block, 512-d chunk: grid 540x4 (~8 blocks/CU -> TLP hides latency;
// round-8 lesson: 2-deep pipeline alone can't). v[64] flat acc, compile-time
// indices only (rule #20). Split-butterfly reduce, float2 store.
__global__ __launch_bounds__(256, 2)
void down_kernel(const float* __restrict__ x,
                 const float* __restrict__ Wd,
                 const int* __restrict__ cnt,
                 const int* __restrict__ tots,
                 const int* __restrict__ map16,
                 const unsigned short* __restrict__ lists,
                 float* __restrict__ hw2,
                 int nTok)
{
    const int bx = blockIdx.x;
    if (bx >= tots[0]) return;
    const int mp = map16[bx];
    const int p = mp >> 16;
    const int tile = mp & 0xffff;
    const int m = min(16, cnt[p] - tile*16);
    int lo = 0, rem = p;
    while (rem >= (NEXP-1-lo)) { rem -= (NEXP-1-lo); ++lo; }
    const int hi = lo + 1 + rem;
    const int ch = blockIdx.y;         // d-chunk 0..3 (512 each)

    const int tid = threadIdx.x;
    const int dg = tid & 31;
    const int u  = tid >> 5;
    const int k  = u >> 2;             // expert slot
    const int tq = u & 3;              // token quad
    const int e  = k ? hi : lo;

    int tks[4];
    #pragma unroll
    for (int i = 0; i < 4; ++i) {
        const int slot = tq*4 + i;
        tks[i] = lists[(size_t)p*nTok + tile*16 + ((slot < m) ? slot : 0)];
    }
    const int dbase = ch*512 + dg;
    const float* x0 = x + (size_t)tks[0]*DMODEL + dbase;
    const float* x1 = x + (size_t)tks[1]*DMODEL + dbase;
    const float* x2 = x + (size_t)tks[2]*DMODEL + dbase;
    const float* x3 = x + (size_t)tks[3]*DMODEL + dbase;
    const float* wp = Wd + (size_t)e*(DMODEL*RANK) + (size_t)dbase*RANK;

    float v[64];                       // v[i*16 + r]
    #pragma unroll
    for (int i = 0; i < 64; ++i) v[i] = 0.f;

    // prefetch iteration 0 into the A set
    float4 wA0 = *(const float4*)(wp + 0);
    float4 wA1 = *(const float4*)(wp + 4);
    float4 wA2 = *(const float4*)(wp + 8);
    float4 wA3 = *(const float4*)(wp + 12);
    float xA0 = x0[0], xA1 = x1[0], xA2 = x2[0], xA3 = x3[0];

    #define FMA16(XV, W0, W1, W2, W3, B)                                \
        v[B+0]  = fmaf(XV, W0.x, v[B+0]);                               \
        v[B+1]  = fmaf(XV, W0.y, v[B+1]);                               \
        v[B+2]  = fmaf(XV, W0.z, v[B+2]);                               \
        v[B+3]  = fmaf(XV, W0.w, v[B+3]);                               \
        v[B+4]  = fmaf(XV, W1.x, v[B+4]);                               \
        v[B+5]  = fmaf(XV, W1.y, v[B+5]);                               \
        v[B+6]  = fmaf(XV, W1.z, v[B+6]);                               \
        v[B+7]  = fmaf(XV, W1.w, v[B+7]);                               \
        v[B+8]  = fmaf(XV, W2.x, v[B+8]);                               \
        v[B+9]  = fmaf(XV, W2.y, v[B+9]);                               \
        v[B+10] = fmaf(XV, W2.z, v[B+10]);                              \
        v[B+11] = fmaf(XV, W2.w, v[B+11]);                              \
        v[B+12] = fmaf(XV, W3.x, v[B+12]);                              \
        v[B+13] = fmaf(XV, W3.y, v[B+13]);                              \
        v[B+14] = fmaf(XV, W3.z, v[B+14]);                              \
        v[B+15] = fmaf(XV, W3.w, v[B+15]);

    for (int jj = 0; jj < 16; jj += 2) {
        // issue iteration jj+1 loads into B, then compute jj from A
        const int dB = (jj + 1) * 32;
        const float* wpb = wp + (size_t)dB * RANK;
        float4 wB0 = *(const float4*)(wpb + 0);
        float4 wB1 = *(const float4*)(wpb + 4);
        float4 wB2 = *(const float4*)(wpb + 8);
        float4 wB3 = *(const float4*)(wpb + 12);
        float xB0 = x0[dB], xB1 = x1[dB], xB2 = x2[dB], xB3 = x3[dB];

        FMA16(xA0, wA0, wA1, wA2, wA3, 0)
        FMA16(xA1, wA0, wA1, wA2, wA3, 16)
        FMA16(xA2, wA0, wA1, wA2, wA3, 32)
        FMA16(xA3, wA0, wA1, wA2, wA3, 48)

        // issue iteration jj+2 loads into A (wraps at the end: harmless reload)
        const int dA = ((jj + 2) & 15) * 32;
        const float* wpa = wp + (size_t)dA * RANK;
        wA0 = *(const float4*)(wpa + 0);
        wA1 = *(const float4*)(wpa + 4);
        wA2 = *(const float4*)(wpa + 8);
        wA3 = *(const float4*)(wpa + 12);
        xA0 = x0[dA]; xA1 = x1[dA]; xA2 = x2[dA]; xA3 = x3[dA];

        FMA16(xB0, wB0, wB1, wB2, wB3, 0)
        FMA16(xB1, wB0, wB1, wB2, wB3, 16)
        FMA16(xB2, wB0, wB1, wB2, wB3, 32)
        FMA16(xB3, wB0, wB1, wB2, wB3, 48)
    }
    #undef FMA16

    // split butterfly: each stage keep half, ship half. compile-time indices only.
    #define RSTAGE(STAGE, HALF)                                        \
    {                                                                  \
        const bool up_ = (dg & STAGE) != 0;                            \
        _Pragma("unroll")                                              \
        for (int j = 0; j < HALF; ++j) {                               \
            const float give = up_ ? v[j] : v[j + HALF];               \
            const float keep = up_ ? v[j + HALF] : v[j];               \
            v[j] = keep + __shfl_xor(give, STAGE);                     \
        }                                                              \
    }
    RSTAGE(1, 32)
    RSTAGE(2, 16)
    RSTAGE(4, 8)
    RSTAGE(8, 4)
    RSTAGE(16, 2)
    #undef RSTAGE

    // lane dg holds sums for idx0, idx0+1:
    const int idx0 = ((dg & 1) << 5) | ((dg & 2) << 3) | ((dg & 4) << 1) |
                     ((dg & 8) >> 1) | ((dg & 16) >> 3);
    const int i_ = idx0 >> 4;          // token within quad
    const int r_ = idx0 & 15;          // even rank
    const int slot = tq*4 + i_;
    if (slot < m) {
        const int tok = (i_ & 2) ? ((i_ & 1) ? tks[3] : tks[2])
                                 : ((i_ & 1) ? tks[1] : tks[0]);
        float2 st; st.x = v[0]; st.y = v[1];
        *(float2*)&hw2[(size_t)tok*(NCH*32) + ch*32 + k*16 + r_] = st;
    }
}

// ---------------- K3: up projection (finalizes h inline, 4-partial gather) ----------------
__global__ __launch_bounds__(256, 2)
void up_kernel(const float* __restrict__ Wu,
               const float* __restrict__ bu,
               const float* __restrict__ bd,
               const float2* __restrict__ wparams,
               const int* __restrict__ cnt,
               const int* __restrict__ tots,
               const int* __restrict__ map32,
               const unsigned short* __restrict__ lists,
               const float* __restrict__ hw2,
               float* __restrict__ out,
               int nTok)
{
    const int bx = blockIdx.x;
    if (bx >= tots[1]) return;
    const int mp = map32[bx];
    const int p = mp >> 16;
    const int tile = mp & 0xffff;
    const int m = min(32, cnt[p] - tile*32);
    int lo = 0, rem = p;
    while (rem >= (NEXP-1-lo)) { rem -= (NEXP-1-lo); ++lo; }
    const int hi = lo + 1 + rem;
    const int cc = blockIdx.y;        // d-chunk of 256

    __shared__ float wu_lds[2][16][256];   // 32 KB
    __shared__ float h_lds[32][36];        // 4.6 KB
    __shared__ float w2_lds[2][32];
    __shared__ int   tok_lds[32];

    const int tid = threadIdx.x;

    if (tid < 32) {
        const int idx = tile*32 + ((tid < m) ? tid : 0);
        const int t = lists[(size_t)p*nTok + idx];
        tok_lds[tid] = t;
        const float2 w = wparams[t];
        w2_lds[0][tid] = (tid < m) ? w.x : 0.f;
        w2_lds[1][tid] = (tid < m) ? w.y : 0.f;
    }

    // stage Wu chunk: direct global->LDS
    #pragma unroll
    for (int i = 0; i < 8; ++i) {
        const int f  = i*1024 + tid*4;   // 0..8191
        const int kk = f >> 12;
        const int rr = (f >> 8) & 15;
        const int dd = f & 255;
        const int es = kk ? hi : lo;
        *(float4*)&wu_lds[kk][rr][dd] =
            *(const float4*)&Wu[(size_t)es*(RANK*DMODEL) + (size_t)rr*DMODEL + cc*256 + dd];
    }
    __syncthreads();

    {   // gather + finalize h' = relu(sum of 4 chunk partials + bd) * w
        const int t8 = tid >> 3;          // token slot 0..31
        const int kk = (tid >> 2) & 1;
        const int rq = tid & 3;
        const int e2 = kk ? hi : lo;
        const float* hp = &hw2[(size_t)tok_lds[t8]*(NCH*32) + kk*16 + rq*4];
        const float4 s0 = *(const float4*)&hp[0];
        const float4 s1 = *(const float4*)&hp[32];
        const float4 s2 = *(const float4*)&hp[64];
        const float4 s3 = *(const float4*)&hp[96];
        const float4 bdv = *(const float4*)&bd[e2*RANK + rq*4];
        const float w = w2_lds[kk][t8];
        float4 h;
        h.x = fmaxf(s0.x + s1.x + s2.x + s3.x + bdv.x, 0.f) * w;
        h.y = fmaxf(s0.y + s1.y + s2.y + s3.y + bdv.y, 0.f) * w;
        h.z = fmaxf(s0.z + s1.z + s2.z + s3.z + bdv.z, 0.f) * w;
        h.w = fmaxf(s0.w + s1.w + s2.w + s3.w + bdv.w, 0.f) * w;
        *(float4*)&h_lds[t8][kk*16 + rq*4] = h;
    }
    __syncthreads();

    const int dg = tid & 31;    // 32 d-groups (4 floats each, two halves)
    const int tq = tid >> 5;    // 8 token quads
    float4 a0[4], a1[4];
    #pragma unroll
    for (int i = 0; i < 4; ++i) { a0[i] = make_float4(0,0,0,0); a1[i] = make_float4(0,0,0,0); }

    #pragma unroll 8
    for (int kr = 0; kr < 32; ++kr) {
        const int kk = kr >> 4, rr = kr & 15;
        const float4 u0 = *(const float4*)&wu_lds[kk][rr][dg*4];
        const float4 u1 = *(const float4*)&wu_lds[kk][rr][128 + dg*4];
        #pragma unroll
        for (int i = 0; i < 4; ++i) {
            const float hv = h_lds[tq*4 + i][kr];
            a0[i].x = fmaf(hv, u0.x, a0[i].x);
            a0[i].y = fmaf(hv, u0.y, a0[i].y);
            a0[i].z = fmaf(hv, u0.z, a0[i].z);
            a0[i].w = fmaf(hv, u0.w, a0[i].w);
            a1[i].x = fmaf(hv, u1.x, a1[i].x);
            a1[i].y = fmaf(hv, u1.y, a1[i].y);
            a1[i].z = fmaf(hv, u1.z, a1[i].z);
            a1[i].w = fmaf(hv, u1.w, a1[i].w);
        }
    }

    const float4 bl0 = *(const float4*)&bu[(size_t)lo*DMODEL + cc*256 + dg*4];
    const float4 bl1 = *(const float4*)&bu[(size_t)lo*DMODEL + cc*256 + 128 + dg*4];
    const float4 bh0 = *(const float4*)&bu[(size_t)hi*DMODEL + cc*256 + dg*4];
    const float4 bh1 = *(const float4*)&bu[(size_t)hi*DMODEL + cc*256 + 128 + dg*4];

    #pragma unroll
    for (int i = 0; i < 4; ++i) {
        const int slot = tq*4 + i;
        if (slot < m) {
            const int t = tok_lds[slot];
            const float wl = w2_lds[0][slot];
            const float wh = w2_lds[1][slot];
            float4 o0 = a0[i], o1 = a1[i];
            o0.x += wl*bl0.x + wh*bh0.x;  o0.y += wl*bl0.y + wh*bh0.y;
            o0.z += wl*bl0.z + wh*bh0.z;  o0.w += wl*bl0.w + wh*bh0.w;
            o1.x += wl*bl1.x + wh*bh1.x;  o1.y += wl*bl1.y + wh*bh1.y;
            o1.z += wl*bl1.z + wh*bh1.z;  o1.w += wl*bl1.w + wh*bh1.w;
            float* op = &out[(size_t)t*DMODEL + cc*256];
            *(float4*)&op[dg*4]       = o0;
            *(float4*)&op[128 + dg*4] = o1;
        }
    }
}

extern "C" void kernel_launch(void* const* d_in, const int* in_sizes, int n_in,
                              void* d_out, int out_size, void* d_ws, size_t ws_size,
                              hipStream_t stream)
{
    (void)n_in; (void)out_size; (void)ws_size;
    const float* x  = (const float*)d_in[0];
    const float* Wr = (const float*)d_in[1];
    const float* br = (const float*)d_in[2];
    const float* Wd = (const float*)d_in[3];
    const float* bd = (const float*)d_in[4];
    const float* Wu = (const float*)d_in[5];
    const float* bu = (const float*)d_in[6];
    float* out = (float*)d_out;
    const int nTok = in_sizes[0] / DMODEL;   // 8192

    const int maxb16 = (nTok + 15)/16 + NPAIR;
    const int maxb32 = (nTok + 31)/32 + NPAIR;

    // ws layout: cnt | tots | map16 | map32 | wparams | lists | hw2
    char* base = (char*)d_ws;
    int* cnt  = (int*)(base);                 // 28 ints
    int* tots = (int*)(base + 128);           // 2 ints
    size_t off = 256;
    int* map16 = (int*)(base + off);
    off += (size_t)maxb16*4; off = (off + 255) & ~(size_t)255;
    int* map32 = (int*)(base + off);
    off += (size_t)maxb32*4; off = (off + 255) & ~(size_t)255;
    float2* wparams = (float2*)(base + off);
    off += (size_t)nTok*sizeof(float2);
    unsigned short* lists = (unsigned short*)(base + off);
    off += (size_t)NPAIR*nTok*sizeof(unsigned short);
    off = (off + 255) & ~(size_t)255;
    float* hw2 = (float*)(base + off);        // nTok * NCH*32 floats = 4 MB

    hipMemsetAsync(d_ws, 0, 256, stream);
    const int ntiles8 = (nTok + 7)/8;
    router_kernel<<<ntiles8, 256, 0, stream>>>(x, Wr, br, wparams, cnt, lists, nTok);
    prefix_kernel<<<1, 64, 0, stream>>>(cnt, tots, map16, map32);
    dim3 gdown(maxb16, NCH);
    down_kernel<<<gdown, 256, 0, stream>>>(x, Wd, cnt, tots, map16, lists, hw2, nTok);
    dim3 gup(maxb32, 8);
    up_kernel<<<gup, 256, 0, stream>>>(Wu, bu, bd, wparams, cnt, tots, map32, lists, hw2, out, nTok);
}